// Round 13
// baseline (420.079 us; speedup 1.0000x reference)
//
#include <hip/hip_runtime.h>

typedef unsigned short u16;
typedef unsigned int   u32;
typedef __attribute__((ext_vector_type(8))) short short8;
typedef __attribute__((ext_vector_type(4))) float floatx4;

static __device__ __forceinline__ float silu_f(float x){
  return x / (1.f + __expf(-x));
}
static __device__ __forceinline__ float bfu2f(u16 u){
  union { u32 i; float f; } v; v.i = ((u32)u) << 16; return v.f;
}
static __device__ __forceinline__ u16 f2bfu(float f){
  union { float f; u32 i; } v; v.f = f;
  u32 x = v.i;
  u32 r = (x + 0x7fffu + ((x >> 16) & 1u)) >> 16;   // round-nearest-even
  return (u16)r;
}
static __device__ __forceinline__ float softplus_f(float v){
  return fmaxf(v, 0.f) + log1pf(__expf(-fabsf(v)));
}

constexpr int cB = 128, cNP = 64, cP = 128, cDIM = 512, cDIN = 1024;
constexpr int cDST = 16, cDTR = 32, cNCLS = 32;
constexpr int cBL = cB * cNP;      // 8192 (b,l) rows
constexpr int cXZ = 2 * cDIN;      // 2048
constexpr long cPSTR = (long)cBL * 64;   // xpart chunk stride (floats)

// ---------------------------------------------------------------------------
// K0: merged fp32 -> bf16 conversion (4 weight tensors; slot 5 unused).
// ---------------------------------------------------------------------------
__global__ __launch_bounds__(256) void k_f2bf_all(
    const float* __restrict__ s0, u16* __restrict__ d0, int n0,
    const float* __restrict__ s1, u16* __restrict__ d1, int n1,
    const float* __restrict__ s2, u16* __restrict__ d2, int n2,
    const float* __restrict__ s3, u16* __restrict__ d3, int n3,
    const float* __restrict__ s4, u16* __restrict__ d4, int n4)
{
  int i = blockIdx.x * 256 + threadIdx.x;
  const float* s; u16* d;
  if (i < n0) { s = s0; d = d0; }
  else {
    i -= n0;
    if (i < n1) { s = s1; d = d1; }
    else {
      i -= n1;
      if (i < n2) { s = s2; d = d2; }
      else {
        i -= n2;
        if (i < n3) { s = s3; d = d3; }
        else {
          i -= n3;
          if (i >= n4) return;
          s = s4; d = d4;
        }
      }
    }
  }
  const size_t off = (size_t)i * 4;
  float4 v = *(const float4*)(s + off);
  ushort4 o;
  o.x = f2bfu(v.x); o.y = f2bfu(v.y); o.z = f2bfu(v.z); o.w = f2bfu(v.w);
  *(ushort4*)(d + off) = o;
}

// ---------------------------------------------------------------------------
// K0b: seg_w[n,p,d] -> wsegT[n,d,p] (bf16). 32x32 tiles, 256 threads.
// ---------------------------------------------------------------------------
__global__ __launch_bounds__(256) void k_segT(
    const float* __restrict__ src, u16* __restrict__ dst)
{
  const int n = blockIdx.z;
  const int p0 = blockIdx.x * 32;
  const int d0 = blockIdx.y * 32;
  const int tx = threadIdx.x & 31;
  const int ty = threadIdx.x >> 5;     // 0..7
  __shared__ float t[32][33];
#pragma unroll
  for (int r = 0; r < 4; ++r)
    t[ty + r * 8][tx] = src[(size_t)n * (cP * cDIM) + (p0 + ty + r * 8) * cDIM + d0 + tx];
  __syncthreads();
#pragma unroll
  for (int r = 0; r < 4; ++r)
    dst[(size_t)n * (cDIM * cP) + (d0 + ty + r * 8) * cP + p0 + tx] =
        f2bfu(t[tx][ty + r * 8]);
}

// ---------------------------------------------------------------------------
// K2: bf16 MFMA GEMM, software-pipelined (register double-buffer).
// C[M,N] = A[M,K] * W[N,K]^T. 128x128 tile, BK=32, 4 waves (2x2 of 64x64).
// AMODE=0: bf16 A. AMODE=1: fp32 A converted in staging.
// EPI=2: u-half tiles (bn<1024) -> TRANSPOSED sU (aliases As/Ws) -> causal
//        conv + SiLU -> ucp; z-half tiles write Cb. bz batching via azs/wzs/czs.
// ---------------------------------------------------------------------------
template<int AMODE, int EPI>
__global__ __launch_bounds__(256) void k_gemm_mfma(
    const void* __restrict__ Av, int lda,
    const u16* __restrict__ W,
    float* __restrict__ C, int ldc,
    u16* __restrict__ Cb, int ldcb,
    int K, long azs, long wzs, long czs,
    const float* __restrict__ cwp, const float* __restrict__ cbp,
    u16* __restrict__ ucp)
{
  constexpr int LDT = 40;            // 32 + 8 pad (u16) -> conflict-free
  constexpr int SU_LD = 136;         // transposed sU row stride (16B aligned)
  constexpr int GEMM_SM = 2 * 128 * LDT;                 // 10240 u16
  constexpr int SM_SZ = (EPI == 2) ? (128 * SU_LD) : GEMM_SM;
  __shared__ __align__(16) u16 smem[SM_SZ];
  u16* As = smem;
  u16* Ws = smem + 128 * LDT;

  const int bz = blockIdx.z;
  const u16* Wz = W + (size_t)bz * wzs;

  const int tid = threadIdx.x;
  const int bm = blockIdx.x * 128;
  const int bn = blockIdx.y * 128;
  const int wave = tid >> 6;
  const int lane = tid & 63;
  const int wm = (wave & 1) * 64;
  const int wn = (wave >> 1) * 64;
  const int l15 = lane & 15;
  const int quad = lane >> 4;

  floatx4 acc[4][4];
#pragma unroll
  for (int i = 0; i < 4; ++i)
#pragma unroll
    for (int j = 0; j < 4; ++j) acc[i][j] = (floatx4){0.f, 0.f, 0.f, 0.f};

  const int r0 = tid >> 2;          // 0..63
  const int c0 = (tid & 3) * 8;     // 0,8,16,24

  const float* Af = (const float*)Av + (AMODE == 1 ? (size_t)bz * azs : 0);
  const u16*   Ab = (const u16*)Av + (AMODE == 0 ? (size_t)bz * azs : 0);

  float4 fa0, fb0, fa1, fb1;        // fp32 staging regs
  short8 ra0, ra1, rw0, rw1;        // bf16 staging regs

  // prologue: load tile 0
  if constexpr (AMODE == 1) {
    const float* p0 = Af + (size_t)(bm + r0) * lda + c0;
    const float* p1 = Af + (size_t)(bm + r0 + 64) * lda + c0;
    fa0 = *(const float4*)p0; fb0 = *(const float4*)(p0 + 4);
    fa1 = *(const float4*)p1; fb1 = *(const float4*)(p1 + 4);
  } else {
    ra0 = *(const short8*)(Ab + (size_t)(bm + r0)      * lda + c0);
    ra1 = *(const short8*)(Ab + (size_t)(bm + r0 + 64) * lda + c0);
  }
  rw0 = *(const short8*)(Wz + (size_t)(bn + r0)      * K + c0);
  rw1 = *(const short8*)(Wz + (size_t)(bn + r0 + 64) * K + c0);

  for (int k0 = 0; k0 < K; k0 += 32) {
    // stage regs -> LDS
    if constexpr (AMODE == 1) {
      short8 s0, s1;
      s0[0] = (short)f2bfu(fa0.x); s0[1] = (short)f2bfu(fa0.y);
      s0[2] = (short)f2bfu(fa0.z); s0[3] = (short)f2bfu(fa0.w);
      s0[4] = (short)f2bfu(fb0.x); s0[5] = (short)f2bfu(fb0.y);
      s0[6] = (short)f2bfu(fb0.z); s0[7] = (short)f2bfu(fb0.w);
      s1[0] = (short)f2bfu(fa1.x); s1[1] = (short)f2bfu(fa1.y);
      s1[2] = (short)f2bfu(fa1.z); s1[3] = (short)f2bfu(fa1.w);
      s1[4] = (short)f2bfu(fb1.x); s1[5] = (short)f2bfu(fb1.y);
      s1[6] = (short)f2bfu(fb1.z); s1[7] = (short)f2bfu(fb1.w);
      *(short8*)&As[r0 * LDT + c0] = s0;
      *(short8*)&As[(r0 + 64) * LDT + c0] = s1;
    } else {
      *(short8*)&As[r0 * LDT + c0] = ra0;
      *(short8*)&As[(r0 + 64) * LDT + c0] = ra1;
    }
    *(short8*)&Ws[r0 * LDT + c0] = rw0;
    *(short8*)&Ws[(r0 + 64) * LDT + c0] = rw1;
    __syncthreads();

    // issue next tile's global loads (overlap with ds_read + MFMA below)
    const int kn = k0 + 32;
    if (kn < K) {
      if constexpr (AMODE == 1) {
        const float* p0 = Af + (size_t)(bm + r0) * lda + kn + c0;
        const float* p1 = Af + (size_t)(bm + r0 + 64) * lda + kn + c0;
        fa0 = *(const float4*)p0; fb0 = *(const float4*)(p0 + 4);
        fa1 = *(const float4*)p1; fb1 = *(const float4*)(p1 + 4);
      } else {
        ra0 = *(const short8*)(Ab + (size_t)(bm + r0)      * lda + kn + c0);
        ra1 = *(const short8*)(Ab + (size_t)(bm + r0 + 64) * lda + kn + c0);
      }
      rw0 = *(const short8*)(Wz + (size_t)(bn + r0)      * K + kn + c0);
      rw1 = *(const short8*)(Wz + (size_t)(bn + r0 + 64) * K + kn + c0);
    }

    short8 af[4], bf[4];
#pragma unroll
    for (int i = 0; i < 4; ++i)
      af[i] = *(const short8*)&As[(wm + i * 16 + l15) * LDT + quad * 8];
#pragma unroll
    for (int j = 0; j < 4; ++j)
      bf[j] = *(const short8*)&Ws[(wn + j * 16 + l15) * LDT + quad * 8];
#pragma unroll
    for (int i = 0; i < 4; ++i)
#pragma unroll
      for (int j = 0; j < 4; ++j)
        acc[i][j] = __builtin_amdgcn_mfma_f32_16x16x32_bf16(
            af[i], bf[j], acc[i][j], 0, 0, 0);
    __syncthreads();
  }

  if constexpr (EPI == 2) {
    if (bn < cDIN) {
      // u-half tile: acc -> transposed sU (bf16), then causal conv + SiLU
      u16* sU = smem;
#pragma unroll
      for (int i = 0; i < 4; ++i) {
        const int mi = wm + i * 16 + quad * 4;
#pragma unroll
        for (int j = 0; j < 4; ++j) {
          const int nj = wn + j * 16 + l15;
          ushort4 pk;
          pk.x = f2bfu(acc[i][j][0]); pk.y = f2bfu(acc[i][j][1]);
          pk.z = f2bfu(acc[i][j][2]); pk.w = f2bfu(acc[i][j][3]);
          *(ushort4*)&sU[nj * SU_LD + mi] = pk;
        }
      }
      __syncthreads();
      const int c = tid & 127;          // tile column (channel offset)
      const int s = tid >> 7;           // sequence 0/1 within tile
      const int b = (bm >> 6) + s;      // global batch
      const int d = bn + c;             // global channel
      const float w0 = cwp[d * 4 + 0], w1 = cwp[d * 4 + 1];
      const float w2 = cwp[d * 4 + 2], w3 = cwp[d * 4 + 3];
      const float cbias = cbp[d];
      u16* dst = ucp + (size_t)b * cNP * cDIN + d;
      const u16* col = &sU[c * SU_LD + s * 64];
      float u0 = 0.f, u1 = 0.f, u2 = 0.f;
      for (int c8 = 0; c8 < 8; ++c8) {
        short8 v8 = *(const short8*)&col[c8 * 8];
        u16 o[8];
#pragma unroll
        for (int i = 0; i < 8; ++i) {
          float u3 = bfu2f((u16)v8[i]);
          float v = w0 * u0 + w1 * u1 + w2 * u2 + w3 * u3 + cbias;
          o[i] = f2bfu(silu_f(v));
          u0 = u1; u1 = u2; u2 = u3;
        }
#pragma unroll
        for (int i = 0; i < 8; ++i)
          dst[(size_t)(c8 * 8 + i) * cDIN] = o[i];
      }
      return;
    }
  }

#pragma unroll
  for (int i = 0; i < 4; ++i) {
    const int m0 = bm + wm + i * 16 + quad * 4;
#pragma unroll
    for (int j = 0; j < 4; ++j) {
      const int n = bn + wn + j * 16 + l15;
      if (C) {
#pragma unroll
        for (int r = 0; r < 4; ++r)
          C[(size_t)(m0 + r) * ldc + n + bz * czs] = acc[i][j][r];
      }
      if (Cb) {
#pragma unroll
        for (int r = 0; r < 4; ++r)
          Cb[(size_t)(m0 + r) * ldcb + n + bz * czs] = f2bfu(acc[i][j][r]);
      }
    }
  }
}

// ---------------------------------------------------------------------------
// K1b: per-row LayerNorm (512 elems), wave per row -> bf16 out.
// seg_b[n,d] added before stats (faithful to reference).
// ---------------------------------------------------------------------------
__global__ __launch_bounds__(256) void k_ln(
    const float* __restrict__ xs, const float* __restrict__ sb,
    const float* __restrict__ ln_g, const float* __restrict__ ln_b,
    u16* __restrict__ x0b)
{
  const int tid = threadIdx.x;
  const int r = blockIdx.x * 4 + (tid >> 6);   // row (b*64+n)
  const int lane = tid & 63;
  const int d = lane * 8;
  const int n = r & 63;

  const float* row = xs + (size_t)r * cDIM + d;
  float4 a = *(const float4*)row;
  float4 b = *(const float4*)(row + 4);
  const float* sbp = sb + n * cDIM + d;
  float4 s0 = *(const float4*)sbp;
  float4 s1 = *(const float4*)(sbp + 4);
  a.x += s0.x; a.y += s0.y; a.z += s0.z; a.w += s0.w;
  b.x += s1.x; b.y += s1.y; b.z += s1.z; b.w += s1.w;

  float s  = a.x + a.y + a.z + a.w + b.x + b.y + b.z + b.w;
  float s2 = a.x*a.x + a.y*a.y + a.z*a.z + a.w*a.w
           + b.x*b.x + b.y*b.y + b.z*b.z + b.w*b.w;
#pragma unroll
  for (int m = 1; m < 64; m <<= 1) {
    s  += __shfl_xor(s,  m, 64);
    s2 += __shfl_xor(s2, m, 64);
  }
  const float mu = s * (1.f / cDIM);
  const float var = s2 * (1.f / cDIM) - mu * mu;
  const float rstd = rsqrtf(var + 1e-5f);

  const float* g = ln_g + n * cDIM + d;
  const float* be = ln_b + n * cDIM + d;
  float4 g0 = *(const float4*)g, g1 = *(const float4*)(g + 4);
  float4 b0 = *(const float4*)be, b1 = *(const float4*)(be + 4);
  ushort4 o0, o1;
  o0.x = f2bfu((a.x - mu) * rstd * g0.x + b0.x);
  o0.y = f2bfu((a.y - mu) * rstd * g0.y + b0.y);
  o0.z = f2bfu((a.z - mu) * rstd * g0.z + b0.z);
  o0.w = f2bfu((a.w - mu) * rstd * g0.w + b0.w);
  o1.x = f2bfu((b.x - mu) * rstd * g1.x + b1.x);
  o1.y = f2bfu((b.y - mu) * rstd * g1.y + b1.y);
  o1.z = f2bfu((b.z - mu) * rstd * g1.z + b1.z);
  o1.w = f2bfu((b.w - mu) * rstd * g1.w + b1.w);
  *(ushort4*)(x0b + (size_t)r * cDIM + d) = o0;
  *(ushort4*)(x0b + (size_t)r * cDIM + d + 4) = o1;
}

// ---------------------------------------------------------------------------
// K4a: x_proj MFMA split-K, pipelined. grid (M/128, 4): K chunks of 256 ->
// xpart[kc][8192][64] fp32. BM=128, BN=64, 128 threads = 2 waves.
// ---------------------------------------------------------------------------
__global__ __launch_bounds__(128) void k_xproj(
    const u16* __restrict__ A, const u16* __restrict__ W,
    float* __restrict__ xpart)
{
  constexpr int LDT = 40;
  __shared__ __align__(16) u16 As[128 * LDT];
  __shared__ __align__(16) u16 Ws[64 * LDT];

  const int tid = threadIdx.x;
  const int bm = blockIdx.x * 128;
  const int kbase = blockIdx.y * 256;
  const int wave = tid >> 6;
  const int lane = tid & 63;
  const int wm = wave * 64;
  const int l15 = lane & 15;
  const int quad = lane >> 4;

  floatx4 acc[4][4];
#pragma unroll
  for (int i = 0; i < 4; ++i)
#pragma unroll
    for (int j = 0; j < 4; ++j) acc[i][j] = (floatx4){0.f, 0.f, 0.f, 0.f};

  short8 rA[4], rW[2];
#pragma unroll
  for (int it = 0; it < 4; ++it) {
    int idx = tid + it * 128, row = idx >> 2, cc = (idx & 3) * 8;
    rA[it] = *(const short8*)(A + (size_t)(bm + row) * cDIN + kbase + cc);
  }
#pragma unroll
  for (int it = 0; it < 2; ++it) {
    int idx = tid + it * 128, row = idx >> 2, cc = (idx & 3) * 8;
    rW[it] = *(const short8*)(W + (size_t)row * cDIN + kbase + cc);
  }

  for (int kk = 0; kk < 256; kk += 32) {
#pragma unroll
    for (int it = 0; it < 4; ++it) {
      int idx = tid + it * 128, row = idx >> 2, cc = (idx & 3) * 8;
      *(short8*)&As[row * LDT + cc] = rA[it];
    }
#pragma unroll
    for (int it = 0; it < 2; ++it) {
      int idx = tid + it * 128, row = idx >> 2, cc = (idx & 3) * 8;
      *(short8*)&Ws[row * LDT + cc] = rW[it];
    }
    __syncthreads();

    if (kk + 32 < 256) {
      const int k0 = kbase + kk + 32;
#pragma unroll
      for (int it = 0; it < 4; ++it) {
        int idx = tid + it * 128, row = idx >> 2, cc = (idx & 3) * 8;
        rA[it] = *(const short8*)(A + (size_t)(bm + row) * cDIN + k0 + cc);
      }
#pragma unroll
      for (int it = 0; it < 2; ++it) {
        int idx = tid + it * 128, row = idx >> 2, cc = (idx & 3) * 8;
        rW[it] = *(const short8*)(W + (size_t)row * cDIN + k0 + cc);
      }
    }

    short8 af[4], bf[4];
#pragma unroll
    for (int i = 0; i < 4; ++i)
      af[i] = *(const short8*)&As[(wm + i * 16 + l15) * LDT + quad * 8];
#pragma unroll
    for (int j = 0; j < 4; ++j)
      bf[j] = *(const short8*)&Ws[(j * 16 + l15) * LDT + quad * 8];
#pragma unroll
    for (int i = 0; i < 4; ++i)
#pragma unroll
      for (int j = 0; j < 4; ++j)
        acc[i][j] = __builtin_amdgcn_mfma_f32_16x16x32_bf16(
            af[i], bf[j], acc[i][j], 0, 0, 0);
    __syncthreads();
  }

  float* out = xpart + (size_t)blockIdx.y * cPSTR;
#pragma unroll
  for (int i = 0; i < 4; ++i) {
    const int m0 = bm + wm + i * 16 + quad * 4;
#pragma unroll
    for (int j = 0; j < 4; ++j) {
      const int n = j * 16 + l15;
#pragma unroll
      for (int r = 0; r < 4; ++r)
        out[(size_t)(m0 + r) * 64 + n] = acc[i][j][r];
    }
  }
}

// ---------------------------------------------------------------------------
// K6: fused dt_proj + selective scan + gate. Stages dt (cols 0:32) AND B/C
// (cols 32:64) from the 4 xpart partials (summed in xred order). Per step:
// delta = softplus(dot32(sDT[l], wdt_regs) + bdt[d]) computed inline (fp32,
// broadcast LDS reads). z bf16 from xz16, uc bf16, y bf16 in place.
// grid (b, 4). Geom fast path (A[n]=(n+1)A[0]) with power tree + 4 y accs.
// ---------------------------------------------------------------------------
__global__ __launch_bounds__(256) void k_scan(
    const u16* __restrict__ xz16, u16* __restrict__ uc,
    const float* __restrict__ xpart, const float* __restrict__ A_log,
    const float* __restrict__ Dp, const float* __restrict__ wdt,
    const float* __restrict__ bdt)
{
  const int b = blockIdx.x;
  const int tid = threadIdx.x;      // 0..255
  const int d = blockIdx.y * 256 + tid;

  __shared__ float sDT[cNP][32];    // dt rows
  __shared__ float sBC[cNP][32];    // [l][0:16]=B, [16:32]=C
  {
    for (int i = tid; i < cNP * 16; i += 256) {
      int l = i >> 4, q = i & 15;
      const float* p = xpart + (size_t)(b * cNP + l) * 64 + q * 4;
      float4 s = *(const float4*)p;
#pragma unroll
      for (int kc = 1; kc < 4; ++kc) {
        float4 v = *(const float4*)(p + (size_t)kc * cPSTR);
        s.x += v.x; s.y += v.y; s.z += v.z; s.w += v.w;
      }
      if (q < 8) *(float4*)&sDT[l][q * 4] = s;
      else       *(float4*)&sBC[l][(q - 8) * 4] = s;
    }
  }

  float wd[cDTR];
  {
    const float4* wp = (const float4*)(wdt + (size_t)d * cDTR);
#pragma unroll
    for (int q = 0; q < 8; ++q) {
      float4 w = wp[q];
      wd[q*4+0] = w.x; wd[q*4+1] = w.y; wd[q*4+2] = w.z; wd[q*4+3] = w.w;
    }
  }
  const float bdtv = bdt[d];

  float A[cDST];
  {
    const float4* ap = (const float4*)(A_log + (size_t)d * cDST);
#pragma unroll
    for (int q = 0; q < 4; ++q) {
      float4 w = ap[q];
      A[q*4+0] = -__expf(w.x); A[q*4+1] = -__expf(w.y);
      A[q*4+2] = -__expf(w.z); A[q*4+3] = -__expf(w.w);
    }
  }
  const float a1 = A[0];
  bool geom = true;
#pragma unroll
  for (int n = 1; n < cDST; ++n)
    geom = geom && (fabsf(A[n] - (float)(n + 1) * a1) <= 1e-4f * fabsf(A[n]));

  float h[cDST];
#pragma unroll
  for (int n = 0; n < cDST; ++n) h[n] = 0.f;
  const float Dv = Dp[d];
  __syncthreads();

  const u16* zsrc = xz16 + cDIN + d;     // z
  u16* usrc = uc + d;                    // uc / y (bf16)
  const size_t rb = (size_t)b * cNP;

  float zvc[8], uvc[8];
#pragma unroll
  for (int i = 0; i < 8; ++i) {
    zvc[i] = bfu2f(zsrc[(rb + i) * cXZ]);
    uvc[i] = bfu2f(usrc[(rb + i) * cDIN]);
  }

  if (geom) {
    for (int c = 0; c < 8; ++c) {
      float zvn[8], uvn[8];
      if (c < 7) {
#pragma unroll
        for (int i = 0; i < 8; ++i) {
          const size_t row = rb + (c + 1) * 8 + i;
          zvn[i] = bfu2f(zsrc[row * cXZ]);
          uvn[i] = bfu2f(usrc[row * cDIN]);
        }
      }
      u16 yo[8];
#pragma unroll
      for (int i = 0; i < 8; ++i) {
        const int l = c * 8 + i;
        // inline dt_proj + softplus (broadcast LDS reads of sDT[l])
        float a0 = 0.f, a1s = 0.f, a2 = 0.f, a3 = 0.f;
#pragma unroll
        for (int k = 0; k < cDTR; k += 4) {
          a0 += sDT[l][k+0] * wd[k+0];
          a1s += sDT[l][k+1] * wd[k+1];
          a2 += sDT[l][k+2] * wd[k+2];
          a3 += sDT[l][k+3] * wd[k+3];
        }
        const float dv = softplus_f((a0 + a1s) + (a2 + a3) + bdtv);
        const float zv = zvc[i], uv = uvc[i];
        const float du = dv * uv;
        const float e1 = __expf(dv * a1);
        const float e2 = e1 * e1;
        const float e4 = e2 * e2;
        float p0 = e1, p1 = e2, p2 = e2 * e1, p3 = e4;
        float y0 = 0.f, y1 = 0.f, y2 = 0.f, y3 = 0.f;
#pragma unroll
        for (int g = 0; g < 4; ++g) {
          const int n = g * 4;
          h[n+0] = p0 * h[n+0] + du * sBC[l][n+0];
          y0 += h[n+0] * sBC[l][16 + n+0];
          h[n+1] = p1 * h[n+1] + du * sBC[l][n+1];
          y1 += h[n+1] * sBC[l][16 + n+1];
          h[n+2] = p2 * h[n+2] + du * sBC[l][n+2];
          y2 += h[n+2] * sBC[l][16 + n+2];
          h[n+3] = p3 * h[n+3] + du * sBC[l][n+3];
          y3 += h[n+3] * sBC[l][16 + n+3];
          if (g < 3) { p0 *= e4; p1 *= e4; p2 *= e4; p3 *= e4; }
        }
        float y = (y0 + y1) + (y2 + y3);
        y = (y + uv * Dv) * silu_f(zv);
        yo[i] = f2bfu(y);
      }
#pragma unroll
      for (int i = 0; i < 8; ++i)
        usrc[(rb + c * 8 + i) * cDIN] = yo[i];
      if (c < 7) {
#pragma unroll
        for (int i = 0; i < 8; ++i) { zvc[i] = zvn[i]; uvc[i] = uvn[i]; }
      }
    }
  } else {
    for (int c = 0; c < 8; ++c) {
      float zvn[8], uvn[8];
      if (c < 7) {
#pragma unroll
        for (int i = 0; i < 8; ++i) {
          const size_t row = rb + (c + 1) * 8 + i;
          zvn[i] = bfu2f(zsrc[row * cXZ]);
          uvn[i] = bfu2f(usrc[row * cDIN]);
        }
      }
      u16 yo[8];
#pragma unroll
      for (int i = 0; i < 8; ++i) {
        const int l = c * 8 + i;
        float a0 = 0.f, a1s = 0.f, a2 = 0.f, a3 = 0.f;
#pragma unroll
        for (int k = 0; k < cDTR; k += 4) {
          a0 += sDT[l][k+0] * wd[k+0];
          a1s += sDT[l][k+1] * wd[k+1];
          a2 += sDT[l][k+2] * wd[k+2];
          a3 += sDT[l][k+3] * wd[k+3];
        }
        const float dv = softplus_f((a0 + a1s) + (a2 + a3) + bdtv);
        const float zv = zvc[i], uv = uvc[i];
        const float du = dv * uv;
        float y0 = 0.f, y1 = 0.f, y2 = 0.f, y3 = 0.f;
#pragma unroll
        for (int n = 0; n < cDST; n += 4) {
          float dA0 = __expf(dv * A[n+0]);
          float dA1 = __expf(dv * A[n+1]);
          float dA2 = __expf(dv * A[n+2]);
          float dA3 = __expf(dv * A[n+3]);
          h[n+0] = dA0 * h[n+0] + du * sBC[l][n+0];
          y0 += h[n+0] * sBC[l][16 + n+0];
          h[n+1] = dA1 * h[n+1] + du * sBC[l][n+1];
          y1 += h[n+1] * sBC[l][16 + n+1];
          h[n+2] = dA2 * h[n+2] + du * sBC[l][n+2];
          y2 += h[n+2] * sBC[l][16 + n+2];
          h[n+3] = dA3 * h[n+3] + du * sBC[l][n+3];
          y3 += h[n+3] * sBC[l][16 + n+3];
        }
        float y = (y0 + y1) + (y2 + y3);
        y = (y + uv * Dv) * silu_f(zv);
        yo[i] = f2bfu(y);
      }
#pragma unroll
      for (int i = 0; i < 8; ++i)
        usrc[(rb + c * 8 + i) * cDIN] = yo[i];
      if (c < 7) {
#pragma unroll
        for (int i = 0; i < 8; ++i) { zvc[i] = zvn[i]; uvc[i] = uvn[i]; }
      }
    }
  }
}

// ---------------------------------------------------------------------------
// K7a: head LN partial sums over bf16 x. grid (b, 8) -> pst[(b*8+chunk)*2+{0,1}]
// ---------------------------------------------------------------------------
__global__ __launch_bounds__(256) void k_hstats1(
    const u16* __restrict__ x, float* __restrict__ pst)
{
  const int b = blockIdx.x;
  const int chunk = blockIdx.y;
  const int tid = threadIdx.x;
  const short8* r8 = (const short8*)(x + (size_t)b * (cNP * cDIM) + chunk * 4096);
  short8 v = r8[tid];
  short8 w = r8[tid + 256];
  float s = 0.f, s2 = 0.f;
#pragma unroll
  for (int i = 0; i < 8; ++i) {
    float f = bfu2f((u16)v[i]); s += f; s2 += f * f;
    float g = bfu2f((u16)w[i]); s += g; s2 += g * g;
  }
  __shared__ float red[512];
  red[tid] = s; red[256 + tid] = s2;
  __syncthreads();
  for (int st = 128; st > 0; st >>= 1) {
    if (tid < st) { red[tid] += red[tid + st]; red[256+tid] += red[256+tid+st]; }
    __syncthreads();
  }
  if (tid == 0) {
    pst[(b * 8 + chunk) * 2]     = red[0];
    pst[(b * 8 + chunk) * 2 + 1] = red[256];
  }
}

// ---------------------------------------------------------------------------
// K8a: head split-K stage 1 (stats finalize folded in), bf16 x.
// grid (b, 16) -> hpart[(b*16+chunk)*32 + cls]
// ---------------------------------------------------------------------------
__global__ __launch_bounds__(256) void k_head1(
    const u16* __restrict__ x, const float* __restrict__ pst,
    const float* __restrict__ hg, const float* __restrict__ hb,
    const u16* __restrict__ hwb, float* __restrict__ hpart)
{
  const int b = blockIdx.x;
  const int chunk = blockIdx.y;
  const int tid = threadIdx.x;

  float s = 0.f, s2 = 0.f;
#pragma unroll
  for (int c = 0; c < 8; ++c) {
    s  += pst[(b * 8 + c) * 2];
    s2 += pst[(b * 8 + c) * 2 + 1];
  }
  const float mu = s * (1.f / (cNP * cDIM));
  const float var = s2 * (1.f / (cNP * cDIM)) - mu * mu;
  const float rstd = rsqrtf(var + 1e-5f);

  const u16* row = x + (size_t)b * (cNP * cDIM);
  const int k0 = chunk * 2048;

  float acc[cNCLS];
#pragma unroll
  for (int c = 0; c < cNCLS; ++c) acc[c] = 0.f;

#pragma unroll
  for (int it = 0; it < 4; ++it) {
    const int i0 = k0 + it * 512 + tid * 2;
    u32 x2 = *(const u32*)(row + i0);
    float xn0 = (bfu2f((u16)(x2 & 0xffffu)) - mu) * rstd * hg[i0]     + hb[i0];
    float xn1 = (bfu2f((u16)(x2 >> 16))     - mu) * rstd * hg[i0 + 1] + hb[i0 + 1];
#pragma unroll
    for (int c = 0; c < cNCLS; ++c) {
      u32 w2 = *(const u32*)(hwb + (size_t)c * (cNP * cDIM) + i0);
      acc[c] += xn0 * bfu2f((u16)(w2 & 0xffffu)) + xn1 * bfu2f((u16)(w2 >> 16));
    }
  }

  __shared__ float sred[cNCLS * 257];
#pragma unroll
  for (int c = 0; c < cNCLS; ++c) sred[c * 257 + tid] = acc[c];
  __syncthreads();
  if (tid < cNCLS * 8) {
    const int c = tid >> 3, p = tid & 7;
    float ss = 0.f;
#pragma unroll
    for (int i = 0; i < 32; ++i) ss += sred[c * 257 + p * 32 + i];
    ss += __shfl_xor(ss, 1, 64);
    ss += __shfl_xor(ss, 2, 64);
    ss += __shfl_xor(ss, 4, 64);
    if (p == 0) hpart[(size_t)(b * 16 + chunk) * cNCLS + c] = ss;
  }
}

// K8b: head stage 2
__global__ __launch_bounds__(64) void k_head2(
    const float* __restrict__ hpart, const float* __restrict__ hbias,
    float* __restrict__ out)
{
  const int b = blockIdx.x;
  const int c = threadIdx.x;
  if (c < cNCLS) {
    float s = 0.f;
#pragma unroll
    for (int k = 0; k < 16; ++k)
      s += hpart[(size_t)(b * 16 + k) * cNCLS + c];
    out[b * cNCLS + c] = s + hbias[c];
  }
}

// ---------------------------------------------------------------------------
extern "C" void kernel_launch(void* const* d_in, const int* in_sizes, int n_in,
                              void* d_out, int out_size, void* d_ws, size_t ws_size,
                              hipStream_t stream)
{
  (void)in_sizes; (void)n_in; (void)out_size; (void)ws_size;

  const float* series    = (const float*)d_in[0];
  const float* seg_w     = (const float*)d_in[1];
  const float* seg_b     = (const float*)d_in[2];
  const float* ln_g      = (const float*)d_in[3];
  const float* ln_b      = (const float*)d_in[4];
  const float* in_proj_w = (const float*)d_in[5];
  const float* conv_w    = (const float*)d_in[6];
  const float* conv_b    = (const float*)d_in[7];
  const float* x_proj_w  = (const float*)d_in[8];
  const float* dt_proj_w = (const float*)d_in[9];
  const float* dt_proj_b = (const float*)d_in[10];
  const float* A_log     = (const float*)d_in[11];
  const float* Dp        = (const float*)d_in[12];
  const float* out_proj_w= (const float*)d_in[13];
  const float* head_ln_g = (const float*)d_in[14];
  const float* head_ln_b = (const float*)d_in[15];
  const float* head_w    = (const float*)d_in[16];
  const float* head_b    = (const float*)d_in[17];

  // workspace layout (~88 MB)
  u16*   xz16   = (u16*)d_ws;                          // [8192,2048] bf16 (z-half used)
  float* xsegf  = (float*)(xz16 + (size_t)cBL * cXZ);  // [8192,512] f32 (seg GEMM out)
  float* pst    = xsegf + (size_t)cBL * cDIM;          // [2048]
  float* hpart  = pst + 128 * 8 * 2;                   // [65536]
  u16*   x0b    = (u16*)(hpart + 128 * 16 * 32);       // [8192,512]
  u16*   wib    = x0b + (size_t)cBL * cDIM;            // [2,2048,512]
  u16*   wob    = wib + (size_t)2 * (2*cDIN) * cDIM;   // [2,512,1024]
  u16*   wxb    = wob + (size_t)2 * cDIM * cDIN;       // [2,64,1024]
  u16*   wsegT  = wxb + (size_t)2 * 64 * cDIN;         // [64,512,128]
  u16*   ucb16  = wsegT + (size_t)cNP * cDIM * cP;     // [8192,1024]
  u16*   hwb    = ucb16 + (size_t)cBL * cDIN;          // [32,32768]
  // xpart aliases x0b (dead between in_proj read and out_proj write;
  // 8192*512*2B == 4*8192*64*4B == 8.39 MB)
  float* xpart  = (float*)x0b;

  // merged weight conversions (counts in float4 units; total = 4224 * 256)
  k_f2bf_all<<<4224, 256, 0, stream>>>(
      in_proj_w,  wib, (2 * (2*cDIN) * cDIM) / 4,
      out_proj_w, wob, (2 * cDIM * cDIN) / 4,
      x_proj_w,   wxb, (2 * 64 * cDIN) / 4,
      head_w,     hwb, (cNCLS * cNP * cDIM) / 4,
      nullptr, nullptr, 0);
  k_segT<<<dim3(cP/32, cDIM/32, cNP), 256, 0, stream>>>(seg_w, wsegT);

  // seg projection (batched MFMA over n) -> xsegf, then (+seg_b) LN -> x0b
  k_gemm_mfma<1,0><<<dim3(1, cDIM/128, cNP), 256, 0, stream>>>(
      series, cNP * cP, wsegT, xsegf, cNP * cDIM, (u16*)nullptr, 0,
      cP, (long)cP, (long)cDIM * cP, (long)cDIM,
      nullptr, nullptr, nullptr);
  k_ln<<<cBL / 4, 256, 0, stream>>>(xsegf, seg_b, ln_g, ln_b, x0b);

  for (int dep = 0; dep < 2; ++dep) {
    const u16*   wi  = wib + (size_t)dep * (2*cDIN) * cDIM;
    const u16*   wo  = wob + (size_t)dep * cDIM * cDIN;
    const u16*   wx  = wxb + (size_t)dep * 64 * cDIN;
    const float* cwd = conv_w    + (size_t)dep * cDIN * 4;
    const float* cbd = conv_b    + (size_t)dep * cDIN;
    const float* wdt = dt_proj_w + (size_t)dep * cDIN * cDTR;
    const float* bdt = dt_proj_b + (size_t)dep * cDIN;
    const float* Ald = A_log     + (size_t)dep * cDIN * cDST;
    const float* Dd  = Dp        + (size_t)dep * cDIN;

    // in_proj + fused conv/SiLU: u-tiles -> ucb16, z-tiles -> xz16
    k_gemm_mfma<0,2><<<dim3(cBL/128, (2*cDIN)/128), 256, 0, stream>>>(
        x0b, cDIM, wi, (float*)nullptr, 0, xz16, cXZ, cDIM, 0, 0, 0,
        cwd, cbd, ucb16);
    // x_proj split-K: xpart = uc @ wx^T (4 K-chunks)
    k_xproj<<<dim3(cBL / 128, 4), 128, 0, stream>>>(ucb16, wx, xpart);
    // fused dt_proj + scan + gate -> y bf16 into ucb16
    k_scan<<<dim3(cB, 4), 256, 0, stream>>>(xz16, ucb16, xpart, Ald, Dd,
                                            wdt, bdt);
    // out_proj: bf16 x0b (both depths; head consumes bf16)
    k_gemm_mfma<0,0><<<dim3(cBL/128, cDIM/128), 256, 0, stream>>>(
        ucb16, cDIN, wo, (float*)nullptr, 0, x0b, cDIM,
        cDIN, 0, 0, 0, nullptr, nullptr, nullptr);
  }

  k_hstats1<<<dim3(cB, 8), 256, 0, stream>>>(x0b, pst);
  k_head1<<<dim3(cB, 16), 256, 0, stream>>>(x0b, pst, head_ln_g, head_ln_b,
                                            hwb, hpart);
  k_head2<<<cB, 64, 0, stream>>>(hpart, head_b, (float*)d_out);
}

// Round 14
// 386.521 us; speedup vs baseline: 1.0868x; 1.0868x over previous
//
#include <hip/hip_runtime.h>

typedef unsigned short u16;
typedef unsigned int   u32;
typedef __attribute__((ext_vector_type(8))) short short8;
typedef __attribute__((ext_vector_type(4))) float floatx4;

static __device__ __forceinline__ float silu_f(float x){
  return x / (1.f + __expf(-x));
}
static __device__ __forceinline__ float bfu2f(u16 u){
  union { u32 i; float f; } v; v.i = ((u32)u) << 16; return v.f;
}
static __device__ __forceinline__ u16 f2bfu(float f){
  union { float f; u32 i; } v; v.f = f;
  u32 x = v.i;
  u32 r = (x + 0x7fffu + ((x >> 16) & 1u)) >> 16;   // round-nearest-even
  return (u16)r;
}
static __device__ __forceinline__ float softplus_f(float v){
  return fmaxf(v, 0.f) + log1pf(__expf(-fabsf(v)));
}

constexpr int cB = 128, cNP = 64, cP = 128, cDIM = 512, cDIN = 1024;
constexpr int cDST = 16, cDTR = 32, cNCLS = 32;
constexpr int cBL = cB * cNP;      // 8192 (b,l) rows
constexpr int cXZ = 2 * cDIN;      // 2048
constexpr long cPSTR = (long)cBL * 64;   // xpart chunk stride (floats)

// ---------------------------------------------------------------------------
// K0: merged fp32 -> bf16 conversion for all 5 weight tensors.
// ---------------------------------------------------------------------------
__global__ __launch_bounds__(256) void k_f2bf_all(
    const float* __restrict__ s0, u16* __restrict__ d0, int n0,
    const float* __restrict__ s1, u16* __restrict__ d1, int n1,
    const float* __restrict__ s2, u16* __restrict__ d2, int n2,
    const float* __restrict__ s3, u16* __restrict__ d3, int n3,
    const float* __restrict__ s4, u16* __restrict__ d4, int n4)
{
  int i = blockIdx.x * 256 + threadIdx.x;
  const float* s; u16* d;
  if (i < n0) { s = s0; d = d0; }
  else {
    i -= n0;
    if (i < n1) { s = s1; d = d1; }
    else {
      i -= n1;
      if (i < n2) { s = s2; d = d2; }
      else {
        i -= n2;
        if (i < n3) { s = s3; d = d3; }
        else {
          i -= n3;
          if (i >= n4) return;
          s = s4; d = d4;
        }
      }
    }
  }
  const size_t off = (size_t)i * 4;
  float4 v = *(const float4*)(s + off);
  ushort4 o;
  o.x = f2bfu(v.x); o.y = f2bfu(v.y); o.z = f2bfu(v.z); o.w = f2bfu(v.w);
  *(ushort4*)(d + off) = o;
}

// ---------------------------------------------------------------------------
// K0b: seg_w[n,p,d] -> wsegT[n,d,p] (bf16). 32x32 tiles, 256 threads.
// ---------------------------------------------------------------------------
__global__ __launch_bounds__(256) void k_segT(
    const float* __restrict__ src, u16* __restrict__ dst)
{
  const int n = blockIdx.z;
  const int p0 = blockIdx.x * 32;
  const int d0 = blockIdx.y * 32;
  const int tx = threadIdx.x & 31;
  const int ty = threadIdx.x >> 5;     // 0..7
  __shared__ float t[32][33];
#pragma unroll
  for (int r = 0; r < 4; ++r)
    t[ty + r * 8][tx] = src[(size_t)n * (cP * cDIM) + (p0 + ty + r * 8) * cDIM + d0 + tx];
  __syncthreads();
#pragma unroll
  for (int r = 0; r < 4; ++r)
    dst[(size_t)n * (cDIM * cP) + (d0 + ty + r * 8) * cP + p0 + tx] =
        f2bfu(t[tx][ty + r * 8]);
}

// ---------------------------------------------------------------------------
// K2: bf16 MFMA GEMM, software-pipelined (register double-buffer).
// C[M,N] = A[M,K] * W[N,K]^T. 128x128 tile, BK=32, 4 waves (2x2 of 64x64).
// AMODE=0: bf16 A. AMODE=1: fp32 A converted in staging.
// AMODE=2: A = 4 split-K fp32 partials summed in staging (xred order; K=32).
// EPI=1: Cb = bf16(softplus(acc + bias[n])).
// EPI=2: u-half tiles (bn<1024) -> TRANSPOSED sU (aliases As/Ws) -> causal
//        conv + SiLU -> ucp; z-half tiles write Cb. bz batching via azs/wzs/czs.
// ---------------------------------------------------------------------------
template<int AMODE, int EPI>
__global__ __launch_bounds__(256) void k_gemm_mfma(
    const void* __restrict__ Av, int lda,
    const u16* __restrict__ W,
    float* __restrict__ C, int ldc,
    u16* __restrict__ Cb, int ldcb,
    const float* __restrict__ bias,
    int K, long azs, long wzs, long czs,
    const float* __restrict__ cwp, const float* __restrict__ cbp,
    u16* __restrict__ ucp)
{
  constexpr int LDT = 40;            // 32 + 8 pad (u16) -> conflict-free
  constexpr int SU_LD = 136;         // transposed sU row stride (16B aligned)
  constexpr int GEMM_SM = 2 * 128 * LDT;                 // 10240 u16
  constexpr int SM_SZ = (EPI == 2) ? (128 * SU_LD) : GEMM_SM;
  __shared__ __align__(16) u16 smem[SM_SZ];
  u16* As = smem;
  u16* Ws = smem + 128 * LDT;

  const int bz = blockIdx.z;
  const u16* Wz = W + (size_t)bz * wzs;

  const int tid = threadIdx.x;
  const int bm = blockIdx.x * 128;
  const int bn = blockIdx.y * 128;
  const int wave = tid >> 6;
  const int lane = tid & 63;
  const int wm = (wave & 1) * 64;
  const int wn = (wave >> 1) * 64;
  const int l15 = lane & 15;
  const int quad = lane >> 4;

  floatx4 acc[4][4];
#pragma unroll
  for (int i = 0; i < 4; ++i)
#pragma unroll
    for (int j = 0; j < 4; ++j) acc[i][j] = (floatx4){0.f, 0.f, 0.f, 0.f};

  const int r0 = tid >> 2;          // 0..63
  const int c0 = (tid & 3) * 8;     // 0,8,16,24

  const float* Af = (const float*)Av + (AMODE == 1 ? (size_t)bz * azs : 0);
  const u16*   Ab = (const u16*)Av + (AMODE == 0 ? (size_t)bz * azs : 0);

  float4 fa0, fb0, fa1, fb1;        // fp32 staging regs
  short8 ra0, ra1, rw0, rw1;        // bf16 staging regs

  // prologue: load tile 0
  if constexpr (AMODE == 1) {
    const float* p0 = Af + (size_t)(bm + r0) * lda + c0;
    const float* p1 = Af + (size_t)(bm + r0 + 64) * lda + c0;
    fa0 = *(const float4*)p0; fb0 = *(const float4*)(p0 + 4);
    fa1 = *(const float4*)p1; fb1 = *(const float4*)(p1 + 4);
  } else if constexpr (AMODE == 0) {
    ra0 = *(const short8*)(Ab + (size_t)(bm + r0)      * lda + c0);
    ra1 = *(const short8*)(Ab + (size_t)(bm + r0 + 64) * lda + c0);
  }
  rw0 = *(const short8*)(Wz + (size_t)(bn + r0)      * K + c0);
  rw1 = *(const short8*)(Wz + (size_t)(bn + r0 + 64) * K + c0);

  for (int k0 = 0; k0 < K; k0 += 32) {
    // stage regs -> LDS
    if constexpr (AMODE == 1) {
      short8 s0, s1;
      s0[0] = (short)f2bfu(fa0.x); s0[1] = (short)f2bfu(fa0.y);
      s0[2] = (short)f2bfu(fa0.z); s0[3] = (short)f2bfu(fa0.w);
      s0[4] = (short)f2bfu(fb0.x); s0[5] = (short)f2bfu(fb0.y);
      s0[6] = (short)f2bfu(fb0.z); s0[7] = (short)f2bfu(fb0.w);
      s1[0] = (short)f2bfu(fa1.x); s1[1] = (short)f2bfu(fa1.y);
      s1[2] = (short)f2bfu(fa1.z); s1[3] = (short)f2bfu(fa1.w);
      s1[4] = (short)f2bfu(fb1.x); s1[5] = (short)f2bfu(fb1.y);
      s1[6] = (short)f2bfu(fb1.z); s1[7] = (short)f2bfu(fb1.w);
      *(short8*)&As[r0 * LDT + c0] = s0;
      *(short8*)&As[(r0 + 64) * LDT + c0] = s1;
    } else if constexpr (AMODE == 0) {
      *(short8*)&As[r0 * LDT + c0] = ra0;
      *(short8*)&As[(r0 + 64) * LDT + c0] = ra1;
    } else {
      // AMODE==2: sum 4 fp32 partials (rows 64 wide), K==32 (one iter)
      const float* base = (const float*)Av;
#pragma unroll
      for (int h = 0; h < 2; ++h) {
        const float* p = base + (size_t)(bm + r0 + h * 64) * 64 + c0;
        float4 a = *(const float4*)p;
        float4 b = *(const float4*)(p + 4);
#pragma unroll
        for (int kc = 1; kc < 4; ++kc) {
          const float* q = p + (size_t)kc * azs;
          float4 va = *(const float4*)q, vb = *(const float4*)(q + 4);
          a.x += va.x; a.y += va.y; a.z += va.z; a.w += va.w;
          b.x += vb.x; b.y += vb.y; b.z += vb.z; b.w += vb.w;
        }
        short8 st;
        st[0] = (short)f2bfu(a.x); st[1] = (short)f2bfu(a.y);
        st[2] = (short)f2bfu(a.z); st[3] = (short)f2bfu(a.w);
        st[4] = (short)f2bfu(b.x); st[5] = (short)f2bfu(b.y);
        st[6] = (short)f2bfu(b.z); st[7] = (short)f2bfu(b.w);
        *(short8*)&As[(r0 + h * 64) * LDT + c0] = st;
      }
    }
    *(short8*)&Ws[r0 * LDT + c0] = rw0;
    *(short8*)&Ws[(r0 + 64) * LDT + c0] = rw1;
    __syncthreads();

    // issue next tile's global loads (overlap with ds_read + MFMA below)
    const int kn = k0 + 32;
    if (kn < K) {
      if constexpr (AMODE == 1) {
        const float* p0 = Af + (size_t)(bm + r0) * lda + kn + c0;
        const float* p1 = Af + (size_t)(bm + r0 + 64) * lda + kn + c0;
        fa0 = *(const float4*)p0; fb0 = *(const float4*)(p0 + 4);
        fa1 = *(const float4*)p1; fb1 = *(const float4*)(p1 + 4);
      } else if constexpr (AMODE == 0) {
        ra0 = *(const short8*)(Ab + (size_t)(bm + r0)      * lda + kn + c0);
        ra1 = *(const short8*)(Ab + (size_t)(bm + r0 + 64) * lda + kn + c0);
      }
      rw0 = *(const short8*)(Wz + (size_t)(bn + r0)      * K + kn + c0);
      rw1 = *(const short8*)(Wz + (size_t)(bn + r0 + 64) * K + kn + c0);
    }

    short8 af[4], bf[4];
#pragma unroll
    for (int i = 0; i < 4; ++i)
      af[i] = *(const short8*)&As[(wm + i * 16 + l15) * LDT + quad * 8];
#pragma unroll
    for (int j = 0; j < 4; ++j)
      bf[j] = *(const short8*)&Ws[(wn + j * 16 + l15) * LDT + quad * 8];
#pragma unroll
    for (int i = 0; i < 4; ++i)
#pragma unroll
      for (int j = 0; j < 4; ++j)
        acc[i][j] = __builtin_amdgcn_mfma_f32_16x16x32_bf16(
            af[i], bf[j], acc[i][j], 0, 0, 0);
    __syncthreads();
  }

  if constexpr (EPI == 2) {
    if (bn < cDIN) {
      // u-half tile: acc -> transposed sU (bf16), then causal conv + SiLU
      u16* sU = smem;
#pragma unroll
      for (int i = 0; i < 4; ++i) {
        const int mi = wm + i * 16 + quad * 4;
#pragma unroll
        for (int j = 0; j < 4; ++j) {
          const int nj = wn + j * 16 + l15;
          ushort4 pk;
          pk.x = f2bfu(acc[i][j][0]); pk.y = f2bfu(acc[i][j][1]);
          pk.z = f2bfu(acc[i][j][2]); pk.w = f2bfu(acc[i][j][3]);
          *(ushort4*)&sU[nj * SU_LD + mi] = pk;
        }
      }
      __syncthreads();
      const int c = tid & 127;          // tile column (channel offset)
      const int s = tid >> 7;           // sequence 0/1 within tile
      const int b = (bm >> 6) + s;      // global batch
      const int d = bn + c;             // global channel
      const float w0 = cwp[d * 4 + 0], w1 = cwp[d * 4 + 1];
      const float w2 = cwp[d * 4 + 2], w3 = cwp[d * 4 + 3];
      const float cbias = cbp[d];
      u16* dst = ucp + (size_t)b * cNP * cDIN + d;
      const u16* col = &sU[c * SU_LD + s * 64];
      float u0 = 0.f, u1 = 0.f, u2 = 0.f;
      for (int c8 = 0; c8 < 8; ++c8) {
        short8 v8 = *(const short8*)&col[c8 * 8];
        u16 o[8];
#pragma unroll
        for (int i = 0; i < 8; ++i) {
          float u3 = bfu2f((u16)v8[i]);
          float v = w0 * u0 + w1 * u1 + w2 * u2 + w3 * u3 + cbias;
          o[i] = f2bfu(silu_f(v));
          u0 = u1; u1 = u2; u2 = u3;
        }
#pragma unroll
        for (int i = 0; i < 8; ++i)
          dst[(size_t)(c8 * 8 + i) * cDIN] = o[i];
      }
      return;
    }
  }

#pragma unroll
  for (int i = 0; i < 4; ++i) {
    const int m0 = bm + wm + i * 16 + quad * 4;
#pragma unroll
    for (int j = 0; j < 4; ++j) {
      const int n = bn + wn + j * 16 + l15;
      if constexpr (EPI == 1) {
        const float bs = bias[n];
#pragma unroll
        for (int r = 0; r < 4; ++r)
          Cb[(size_t)(m0 + r) * ldcb + n + bz * czs] =
              f2bfu(softplus_f(acc[i][j][r] + bs));
      } else {
        if (C) {
#pragma unroll
          for (int r = 0; r < 4; ++r)
            C[(size_t)(m0 + r) * ldc + n + bz * czs] = acc[i][j][r];
        }
        if (Cb) {
#pragma unroll
          for (int r = 0; r < 4; ++r)
            Cb[(size_t)(m0 + r) * ldcb + n + bz * czs] = f2bfu(acc[i][j][r]);
        }
      }
    }
  }
}

// ---------------------------------------------------------------------------
// K1b: per-row LayerNorm (512 elems), wave per row -> bf16 out.
// seg_b[n,d] added before stats (faithful to reference).
// ---------------------------------------------------------------------------
__global__ __launch_bounds__(256) void k_ln(
    const float* __restrict__ xs, const float* __restrict__ sb,
    const float* __restrict__ ln_g, const float* __restrict__ ln_b,
    u16* __restrict__ x0b)
{
  const int tid = threadIdx.x;
  const int r = blockIdx.x * 4 + (tid >> 6);   // row (b*64+n)
  const int lane = tid & 63;
  const int d = lane * 8;
  const int n = r & 63;

  const float* row = xs + (size_t)r * cDIM + d;
  float4 a = *(const float4*)row;
  float4 b = *(const float4*)(row + 4);
  const float* sbp = sb + n * cDIM + d;
  float4 s0 = *(const float4*)sbp;
  float4 s1 = *(const float4*)(sbp + 4);
  a.x += s0.x; a.y += s0.y; a.z += s0.z; a.w += s0.w;
  b.x += s1.x; b.y += s1.y; b.z += s1.z; b.w += s1.w;

  float s  = a.x + a.y + a.z + a.w + b.x + b.y + b.z + b.w;
  float s2 = a.x*a.x + a.y*a.y + a.z*a.z + a.w*a.w
           + b.x*b.x + b.y*b.y + b.z*b.z + b.w*b.w;
#pragma unroll
  for (int m = 1; m < 64; m <<= 1) {
    s  += __shfl_xor(s,  m, 64);
    s2 += __shfl_xor(s2, m, 64);
  }
  const float mu = s * (1.f / cDIM);
  const float var = s2 * (1.f / cDIM) - mu * mu;
  const float rstd = rsqrtf(var + 1e-5f);

  const float* g = ln_g + n * cDIM + d;
  const float* be = ln_b + n * cDIM + d;
  float4 g0 = *(const float4*)g, g1 = *(const float4*)(g + 4);
  float4 b0 = *(const float4*)be, b1 = *(const float4*)(be + 4);
  ushort4 o0, o1;
  o0.x = f2bfu((a.x - mu) * rstd * g0.x + b0.x);
  o0.y = f2bfu((a.y - mu) * rstd * g0.y + b0.y);
  o0.z = f2bfu((a.z - mu) * rstd * g0.z + b0.z);
  o0.w = f2bfu((a.w - mu) * rstd * g0.w + b0.w);
  o1.x = f2bfu((b.x - mu) * rstd * g1.x + b1.x);
  o1.y = f2bfu((b.y - mu) * rstd * g1.y + b1.y);
  o1.z = f2bfu((b.z - mu) * rstd * g1.z + b1.z);
  o1.w = f2bfu((b.w - mu) * rstd * g1.w + b1.w);
  *(ushort4*)(x0b + (size_t)r * cDIM + d) = o0;
  *(ushort4*)(x0b + (size_t)r * cDIM + d + 4) = o1;
}

// ---------------------------------------------------------------------------
// K4a: x_proj MFMA split-K, pipelined. grid (M/128, 4): K chunks of 256 ->
// xpart[kc][8192][64] fp32. BM=128, BN=64, 128 threads = 2 waves.
// ---------------------------------------------------------------------------
__global__ __launch_bounds__(128) void k_xproj(
    const u16* __restrict__ A, const u16* __restrict__ W,
    float* __restrict__ xpart)
{
  constexpr int LDT = 40;
  __shared__ __align__(16) u16 As[128 * LDT];
  __shared__ __align__(16) u16 Ws[64 * LDT];

  const int tid = threadIdx.x;
  const int bm = blockIdx.x * 128;
  const int kbase = blockIdx.y * 256;
  const int wave = tid >> 6;
  const int lane = tid & 63;
  const int wm = wave * 64;
  const int l15 = lane & 15;
  const int quad = lane >> 4;

  floatx4 acc[4][4];
#pragma unroll
  for (int i = 0; i < 4; ++i)
#pragma unroll
    for (int j = 0; j < 4; ++j) acc[i][j] = (floatx4){0.f, 0.f, 0.f, 0.f};

  short8 rA[4], rW[2];
#pragma unroll
  for (int it = 0; it < 4; ++it) {
    int idx = tid + it * 128, row = idx >> 2, cc = (idx & 3) * 8;
    rA[it] = *(const short8*)(A + (size_t)(bm + row) * cDIN + kbase + cc);
  }
#pragma unroll
  for (int it = 0; it < 2; ++it) {
    int idx = tid + it * 128, row = idx >> 2, cc = (idx & 3) * 8;
    rW[it] = *(const short8*)(W + (size_t)row * cDIN + kbase + cc);
  }

  for (int kk = 0; kk < 256; kk += 32) {
#pragma unroll
    for (int it = 0; it < 4; ++it) {
      int idx = tid + it * 128, row = idx >> 2, cc = (idx & 3) * 8;
      *(short8*)&As[row * LDT + cc] = rA[it];
    }
#pragma unroll
    for (int it = 0; it < 2; ++it) {
      int idx = tid + it * 128, row = idx >> 2, cc = (idx & 3) * 8;
      *(short8*)&Ws[row * LDT + cc] = rW[it];
    }
    __syncthreads();

    if (kk + 32 < 256) {
      const int k0 = kbase + kk + 32;
#pragma unroll
      for (int it = 0; it < 4; ++it) {
        int idx = tid + it * 128, row = idx >> 2, cc = (idx & 3) * 8;
        rA[it] = *(const short8*)(A + (size_t)(bm + row) * cDIN + k0 + cc);
      }
#pragma unroll
      for (int it = 0; it < 2; ++it) {
        int idx = tid + it * 128, row = idx >> 2, cc = (idx & 3) * 8;
        rW[it] = *(const short8*)(W + (size_t)row * cDIN + k0 + cc);
      }
    }

    short8 af[4], bf[4];
#pragma unroll
    for (int i = 0; i < 4; ++i)
      af[i] = *(const short8*)&As[(wm + i * 16 + l15) * LDT + quad * 8];
#pragma unroll
    for (int j = 0; j < 4; ++j)
      bf[j] = *(const short8*)&Ws[(j * 16 + l15) * LDT + quad * 8];
#pragma unroll
    for (int i = 0; i < 4; ++i)
#pragma unroll
      for (int j = 0; j < 4; ++j)
        acc[i][j] = __builtin_amdgcn_mfma_f32_16x16x32_bf16(
            af[i], bf[j], acc[i][j], 0, 0, 0);
    __syncthreads();
  }

  float* out = xpart + (size_t)blockIdx.y * cPSTR;
#pragma unroll
  for (int i = 0; i < 4; ++i) {
    const int m0 = bm + wm + i * 16 + quad * 4;
#pragma unroll
    for (int j = 0; j < 4; ++j) {
      const int n = j * 16 + l15;
#pragma unroll
      for (int r = 0; r < 4; ++r)
        out[(size_t)(m0 + r) * 64 + n] = acc[i][j][r];
    }
  }
}

// ---------------------------------------------------------------------------
// K6: selective scan + (y + uc*D) * silu(z). delta/z bf16 from xz16, uc bf16,
// y bf16 in place. B/C summed from the 4 xpart partials at staging.
// grid (b, 4), chunked-by-8 loads. Geom fast path (A[n]=(n+1)A[0], verified
// per channel) with 4-chain power tree + 4 y accumulators.
// ---------------------------------------------------------------------------
__global__ __launch_bounds__(256) void k_scan(
    const u16* __restrict__ xz16, u16* __restrict__ uc,
    const float* __restrict__ xpart, const float* __restrict__ A_log,
    const float* __restrict__ Dp)
{
  const int b = blockIdx.x;
  const int tid = threadIdx.x;      // 0..255
  const int d = blockIdx.y * 256 + tid;

  __shared__ float sBC[cNP][32];    // [l][0:16]=B, [16:32]=C
  {
    for (int i = tid; i < cNP * 8; i += 256) {
      int l = i >> 3, q = i & 7;
      const float* p = xpart + (size_t)(b * cNP + l) * 64 + 32 + q * 4;
      float4 s = *(const float4*)p;
#pragma unroll
      for (int kc = 1; kc < 4; ++kc) {
        float4 v = *(const float4*)(p + (size_t)kc * cPSTR);
        s.x += v.x; s.y += v.y; s.z += v.z; s.w += v.w;
      }
      *(float4*)&sBC[l][q * 4] = s;
    }
  }

  float A[cDST];
  {
    const float4* ap = (const float4*)(A_log + (size_t)d * cDST);
#pragma unroll
    for (int q = 0; q < 4; ++q) {
      float4 w = ap[q];
      A[q*4+0] = -__expf(w.x); A[q*4+1] = -__expf(w.y);
      A[q*4+2] = -__expf(w.z); A[q*4+3] = -__expf(w.w);
    }
  }
  const float a1 = A[0];
  bool geom = true;
#pragma unroll
  for (int n = 1; n < cDST; ++n)
    geom = geom && (fabsf(A[n] - (float)(n + 1) * a1) <= 1e-4f * fabsf(A[n]));

  float h[cDST];
#pragma unroll
  for (int n = 0; n < cDST; ++n) h[n] = 0.f;
  const float Dv = Dp[d];
  __syncthreads();

  const u16* dsrc = xz16 + d;            // delta at xz16[row*2048 + d]
  const u16* zsrc = xz16 + cDIN + d;     // z
  u16* usrc = uc + d;                    // uc / y (bf16)
  const size_t rb = (size_t)b * cNP;

  float dvc[8], zvc[8], uvc[8];
#pragma unroll
  for (int i = 0; i < 8; ++i) {
    dvc[i] = bfu2f(dsrc[(rb + i) * cXZ]);
    zvc[i] = bfu2f(zsrc[(rb + i) * cXZ]);
    uvc[i] = bfu2f(usrc[(rb + i) * cDIN]);
  }

  if (geom) {
    for (int c = 0; c < 8; ++c) {
      float dvn[8], zvn[8], uvn[8];
      if (c < 7) {
#pragma unroll
        for (int i = 0; i < 8; ++i) {
          const size_t row = rb + (c + 1) * 8 + i;
          dvn[i] = bfu2f(dsrc[row * cXZ]);
          zvn[i] = bfu2f(zsrc[row * cXZ]);
          uvn[i] = bfu2f(usrc[row * cDIN]);
        }
      }
      u16 yo[8];
#pragma unroll
      for (int i = 0; i < 8; ++i) {
        const int l = c * 8 + i;
        const float dv = dvc[i], zv = zvc[i], uv = uvc[i];
        const float du = dv * uv;
        const float e1 = __expf(dv * a1);
        const float e2 = e1 * e1;
        const float e4 = e2 * e2;
        float p0 = e1, p1 = e2, p2 = e2 * e1, p3 = e4;
        float y0 = 0.f, y1 = 0.f, y2 = 0.f, y3 = 0.f;
#pragma unroll
        for (int g = 0; g < 4; ++g) {
          const int n = g * 4;
          h[n+0] = p0 * h[n+0] + du * sBC[l][n+0];
          y0 += h[n+0] * sBC[l][16 + n+0];
          h[n+1] = p1 * h[n+1] + du * sBC[l][n+1];
          y1 += h[n+1] * sBC[l][16 + n+1];
          h[n+2] = p2 * h[n+2] + du * sBC[l][n+2];
          y2 += h[n+2] * sBC[l][16 + n+2];
          h[n+3] = p3 * h[n+3] + du * sBC[l][n+3];
          y3 += h[n+3] * sBC[l][16 + n+3];
          if (g < 3) { p0 *= e4; p1 *= e4; p2 *= e4; p3 *= e4; }
        }
        float y = (y0 + y1) + (y2 + y3);
        y = (y + uv * Dv) * silu_f(zv);
        yo[i] = f2bfu(y);
      }
#pragma unroll
      for (int i = 0; i < 8; ++i)
        usrc[(rb + c * 8 + i) * cDIN] = yo[i];
      if (c < 7) {
#pragma unroll
        for (int i = 0; i < 8; ++i) {
          dvc[i] = dvn[i]; zvc[i] = zvn[i]; uvc[i] = uvn[i];
        }
      }
    }
  } else {
    for (int c = 0; c < 8; ++c) {
      float dvn[8], zvn[8], uvn[8];
      if (c < 7) {
#pragma unroll
        for (int i = 0; i < 8; ++i) {
          const size_t row = rb + (c + 1) * 8 + i;
          dvn[i] = bfu2f(dsrc[row * cXZ]);
          zvn[i] = bfu2f(zsrc[row * cXZ]);
          uvn[i] = bfu2f(usrc[row * cDIN]);
        }
      }
      u16 yo[8];
#pragma unroll
      for (int i = 0; i < 8; ++i) {
        const int l = c * 8 + i;
        const float dv = dvc[i], zv = zvc[i], uv = uvc[i];
        const float du = dv * uv;
        float y0 = 0.f, y1 = 0.f, y2 = 0.f, y3 = 0.f;
#pragma unroll
        for (int n = 0; n < cDST; n += 4) {
          float dA0 = __expf(dv * A[n+0]);
          float dA1 = __expf(dv * A[n+1]);
          float dA2 = __expf(dv * A[n+2]);
          float dA3 = __expf(dv * A[n+3]);
          h[n+0] = dA0 * h[n+0] + du * sBC[l][n+0];
          y0 += h[n+0] * sBC[l][16 + n+0];
          h[n+1] = dA1 * h[n+1] + du * sBC[l][n+1];
          y1 += h[n+1] * sBC[l][16 + n+1];
          h[n+2] = dA2 * h[n+2] + du * sBC[l][n+2];
          y2 += h[n+2] * sBC[l][16 + n+2];
          h[n+3] = dA3 * h[n+3] + du * sBC[l][n+3];
          y3 += h[n+3] * sBC[l][16 + n+3];
        }
        float y = (y0 + y1) + (y2 + y3);
        y = (y + uv * Dv) * silu_f(zv);
        yo[i] = f2bfu(y);
      }
#pragma unroll
      for (int i = 0; i < 8; ++i)
        usrc[(rb + c * 8 + i) * cDIN] = yo[i];
      if (c < 7) {
#pragma unroll
        for (int i = 0; i < 8; ++i) {
          dvc[i] = dvn[i]; zvc[i] = zvn[i]; uvc[i] = uvn[i];
        }
      }
    }
  }
}

// ---------------------------------------------------------------------------
// K7a: head LN partial sums over bf16 x. grid (b, 8) -> pst[(b*8+chunk)*2+{0,1}]
// ---------------------------------------------------------------------------
__global__ __launch_bounds__(256) void k_hstats1(
    const u16* __restrict__ x, float* __restrict__ pst)
{
  const int b = blockIdx.x;
  const int chunk = blockIdx.y;
  const int tid = threadIdx.x;
  const short8* r8 = (const short8*)(x + (size_t)b * (cNP * cDIM) + chunk * 4096);
  short8 v = r8[tid];
  short8 w = r8[tid + 256];
  float s = 0.f, s2 = 0.f;
#pragma unroll
  for (int i = 0; i < 8; ++i) {
    float f = bfu2f((u16)v[i]); s += f; s2 += f * f;
    float g = bfu2f((u16)w[i]); s += g; s2 += g * g;
  }
  __shared__ float red[512];
  red[tid] = s; red[256 + tid] = s2;
  __syncthreads();
  for (int st = 128; st > 0; st >>= 1) {
    if (tid < st) { red[tid] += red[tid + st]; red[256+tid] += red[256+tid+st]; }
    __syncthreads();
  }
  if (tid == 0) {
    pst[(b * 8 + chunk) * 2]     = red[0];
    pst[(b * 8 + chunk) * 2 + 1] = red[256];
  }
}

// ---------------------------------------------------------------------------
// K8a: head split-K stage 1 (stats finalize folded in), bf16 x.
// grid (b, 16) -> hpart[(b*16+chunk)*32 + cls]
// ---------------------------------------------------------------------------
__global__ __launch_bounds__(256) void k_head1(
    const u16* __restrict__ x, const float* __restrict__ pst,
    const float* __restrict__ hg, const float* __restrict__ hb,
    const u16* __restrict__ hwb, float* __restrict__ hpart)
{
  const int b = blockIdx.x;
  const int chunk = blockIdx.y;
  const int tid = threadIdx.x;

  float s = 0.f, s2 = 0.f;
#pragma unroll
  for (int c = 0; c < 8; ++c) {
    s  += pst[(b * 8 + c) * 2];
    s2 += pst[(b * 8 + c) * 2 + 1];
  }
  const float mu = s * (1.f / (cNP * cDIM));
  const float var = s2 * (1.f / (cNP * cDIM)) - mu * mu;
  const float rstd = rsqrtf(var + 1e-5f);

  const u16* row = x + (size_t)b * (cNP * cDIM);
  const int k0 = chunk * 2048;

  float acc[cNCLS];
#pragma unroll
  for (int c = 0; c < cNCLS; ++c) acc[c] = 0.f;

#pragma unroll
  for (int it = 0; it < 4; ++it) {
    const int i0 = k0 + it * 512 + tid * 2;
    u32 x2 = *(const u32*)(row + i0);
    float xn0 = (bfu2f((u16)(x2 & 0xffffu)) - mu) * rstd * hg[i0]     + hb[i0];
    float xn1 = (bfu2f((u16)(x2 >> 16))     - mu) * rstd * hg[i0 + 1] + hb[i0 + 1];
#pragma unroll
    for (int c = 0; c < cNCLS; ++c) {
      u32 w2 = *(const u32*)(hwb + (size_t)c * (cNP * cDIM) + i0);
      acc[c] += xn0 * bfu2f((u16)(w2 & 0xffffu)) + xn1 * bfu2f((u16)(w2 >> 16));
    }
  }

  __shared__ float sred[cNCLS * 257];
#pragma unroll
  for (int c = 0; c < cNCLS; ++c) sred[c * 257 + tid] = acc[c];
  __syncthreads();
  if (tid < cNCLS * 8) {
    const int c = tid >> 3, p = tid & 7;
    float ss = 0.f;
#pragma unroll
    for (int i = 0; i < 32; ++i) ss += sred[c * 257 + p * 32 + i];
    ss += __shfl_xor(ss, 1, 64);
    ss += __shfl_xor(ss, 2, 64);
    ss += __shfl_xor(ss, 4, 64);
    if (p == 0) hpart[(size_t)(b * 16 + chunk) * cNCLS + c] = ss;
  }
}

// K8b: head stage 2
__global__ __launch_bounds__(64) void k_head2(
    const float* __restrict__ hpart, const float* __restrict__ hbias,
    float* __restrict__ out)
{
  const int b = blockIdx.x;
  const int c = threadIdx.x;
  if (c < cNCLS) {
    float s = 0.f;
#pragma unroll
    for (int k = 0; k < 16; ++k)
      s += hpart[(size_t)(b * 16 + k) * cNCLS + c];
    out[b * cNCLS + c] = s + hbias[c];
  }
}

// ---------------------------------------------------------------------------
extern "C" void kernel_launch(void* const* d_in, const int* in_sizes, int n_in,
                              void* d_out, int out_size, void* d_ws, size_t ws_size,
                              hipStream_t stream)
{
  (void)in_sizes; (void)n_in; (void)out_size; (void)ws_size;

  const float* series    = (const float*)d_in[0];
  const float* seg_w     = (const float*)d_in[1];
  const float* seg_b     = (const float*)d_in[2];
  const float* ln_g      = (const float*)d_in[3];
  const float* ln_b      = (const float*)d_in[4];
  const float* in_proj_w = (const float*)d_in[5];
  const float* conv_w    = (const float*)d_in[6];
  const float* conv_b    = (const float*)d_in[7];
  const float* x_proj_w  = (const float*)d_in[8];
  const float* dt_proj_w = (const float*)d_in[9];
  const float* dt_proj_b = (const float*)d_in[10];
  const float* A_log     = (const float*)d_in[11];
  const float* Dp        = (const float*)d_in[12];
  const float* out_proj_w= (const float*)d_in[13];
  const float* head_ln_g = (const float*)d_in[14];
  const float* head_ln_b = (const float*)d_in[15];
  const float* head_w    = (const float*)d_in[16];
  const float* head_b    = (const float*)d_in[17];

  // workspace layout (~90 MB)
  u16*   xz16   = (u16*)d_ws;                          // [8192,2048] bf16 (delta | z)
  float* xsegf  = (float*)(xz16 + (size_t)cBL * cXZ);  // [8192,512] f32 (seg GEMM out)
  float* pst    = xsegf + (size_t)cBL * cDIM;          // [2048]
  float* hpart  = pst + 128 * 8 * 2;                   // [65536]
  u16*   x0b    = (u16*)(hpart + 128 * 16 * 32);       // [8192,512]
  u16*   wib    = x0b + (size_t)cBL * cDIM;            // [2,2048,512]
  u16*   wob    = wib + (size_t)2 * (2*cDIN) * cDIM;   // [2,512,1024]
  u16*   wdtb   = wob + (size_t)2 * cDIM * cDIN;       // [2,1024,32]
  u16*   wxb    = wdtb + (size_t)2 * cDIN * cDTR;      // [2,64,1024]
  u16*   wsegT  = wxb + (size_t)2 * 64 * cDIN;         // [64,512,128]
  u16*   ucb16  = wsegT + (size_t)cNP * cDIM * cP;     // [8192,1024]
  u16*   hwb    = ucb16 + (size_t)cBL * cDIN;          // [32,32768]
  // xpart aliases x0b (dead between in_proj read and out_proj write;
  // 8192*512*2B == 4*8192*64*4B == 8.39 MB)
  float* xpart  = (float*)x0b;

  // merged weight conversions (counts in float4 units; total = 4288 * 256)
  k_f2bf_all<<<4288, 256, 0, stream>>>(
      in_proj_w,  wib,  (2 * (2*cDIN) * cDIM) / 4,
      out_proj_w, wob,  (2 * cDIM * cDIN) / 4,
      dt_proj_w,  wdtb, (2 * cDIN * cDTR) / 4,
      x_proj_w,   wxb,  (2 * 64 * cDIN) / 4,
      head_w,     hwb,  (cNCLS * cNP * cDIM) / 4);
  k_segT<<<dim3(cP/32, cDIM/32, cNP), 256, 0, stream>>>(seg_w, wsegT);

  // seg projection (batched MFMA over n) -> xsegf, then (+seg_b) LN -> x0b
  k_gemm_mfma<1,0><<<dim3(1, cDIM/128, cNP), 256, 0, stream>>>(
      series, cNP * cP, wsegT, xsegf, cNP * cDIM, (u16*)nullptr, 0,
      nullptr, cP, (long)cP, (long)cDIM * cP, (long)cDIM,
      nullptr, nullptr, nullptr);
  k_ln<<<cBL / 4, 256, 0, stream>>>(xsegf, seg_b, ln_g, ln_b, x0b);

  for (int dep = 0; dep < 2; ++dep) {
    const u16*   wi  = wib  + (size_t)dep * (2*cDIN) * cDIM;
    const u16*   wo  = wob  + (size_t)dep * cDIM * cDIN;
    const u16*   wdt = wdtb + (size_t)dep * cDIN * cDTR;
    const u16*   wx  = wxb  + (size_t)dep * 64 * cDIN;
    const float* cwd = conv_w     + (size_t)dep * cDIN * 4;
    const float* cbd = conv_b     + (size_t)dep * cDIN;
    const float* bdt = dt_proj_b  + (size_t)dep * cDIN;
    const float* Ald = A_log      + (size_t)dep * cDIN * cDST;
    const float* Dd  = Dp         + (size_t)dep * cDIN;

    // in_proj + fused conv/SiLU: u-tiles -> ucb16, z-tiles -> xz16
    k_gemm_mfma<0,2><<<dim3(cBL/128, (2*cDIN)/128), 256, 0, stream>>>(
        x0b, cDIM, wi, (float*)nullptr, 0, xz16, cXZ, nullptr, cDIM, 0, 0, 0,
        cwd, cbd, ucb16);
    // x_proj split-K: xpart = uc @ wx^T (4 K-chunks)
    k_xproj<<<dim3(cBL / 128, 4), 128, 0, stream>>>(ucb16, wx, xpart);
    // dt_proj + softplus (sums xpart partials in staging) -> delta into xz16
    k_gemm_mfma<2,1><<<dim3(cBL/128, cDIN/128), 256, 0, stream>>>(
        xpart, 64, wdt, (float*)nullptr, 0, xz16, cXZ, bdt, cDTR,
        cPSTR, 0, 0, nullptr, nullptr, nullptr);
    // scan + gate (B/C summed from xpart at staging) -> y bf16 into ucb16
    k_scan<<<dim3(cB, 4), 256, 0, stream>>>(xz16, ucb16, xpart, Ald, Dd);
    // out_proj: bf16 x0b (both depths; head consumes bf16)
    k_gemm_mfma<0,0><<<dim3(cBL/128, cDIM/128), 256, 0, stream>>>(
        ucb16, cDIN, wo, (float*)nullptr, 0, x0b, cDIM,
        nullptr, cDIN, 0, 0, 0, nullptr, nullptr, nullptr);
  }

  k_hstats1<<<dim3(cB, 8), 256, 0, stream>>>(x0b, pst);
  k_head1<<<dim3(cB, 16), 256, 0, stream>>>(x0b, pst, head_ln_g, head_ln_b,
                                            hwb, hpart);
  k_head2<<<cB, 64, 0, stream>>>(hpart, head_b, (float*)d_out);
}